// Round 4
// baseline (550.303 us; speedup 1.0000x reference)
//
#include <hip/hip_runtime.h>
#include <cstdint>
#include <cstddef>

#define D_DIM 256
#define K_CODES 4096
#define N_ROWS 16384
#define NORM_ROWS_PER_BLK 32

typedef __attribute__((ext_vector_type(4))) int   i32x4;
typedef __attribute__((ext_vector_type(4))) float f32x4;

// ---- bf16 helpers (RNE) ----
__device__ __forceinline__ unsigned short f2bf(float x) {
    const unsigned int u = __float_as_uint(x);
    return (unsigned short)((u + 0x7fffu + ((u >> 16) & 1u)) >> 16);
}
__device__ __forceinline__ float bf2f(unsigned short h) {
    return __uint_as_float((unsigned int)h << 16);
}

// ---- async global->LDS, 16B per lane (dest is wave-uniform base + lane*16) ----
__device__ __forceinline__ void gload16(const unsigned short* g, unsigned short* l) {
    __builtin_amdgcn_global_load_lds(
        (const __attribute__((address_space(1))) void*)g,
        (__attribute__((address_space(3))) void*)l, 16, 0, 0);
}

// ---- inline-asm MFMA: D = A*B + D (gfx950, bf16 16x16x32, 4 VGPR frags) ----
#define MFMA(c, a, b) \
    asm volatile("v_mfma_f32_16x16x32_bf16 %0, %1, %2, %0" : "+v"(c) : "v"(a), "v"(b))

// ---- numpy-pairwise sum of squares of a 128-float block (fp32, no contraction) ----
__device__ __forceinline__ float np_sumsq_128(const float* __restrict__ a)
{
    float r[8];
    #pragma unroll
    for (int j = 0; j < 8; ++j) r[j] = __fmul_rn(a[j], a[j]);
    #pragma unroll
    for (int i = 8; i < 128; i += 8)
        #pragma unroll
        for (int j = 0; j < 8; ++j)
            r[j] = __fadd_rn(r[j], __fmul_rn(a[i + j], a[i + j]));
    return __fadd_rn(__fadd_rn(__fadd_rn(r[0], r[1]), __fadd_rn(r[2], r[3])),
                     __fadd_rn(__fadd_rn(r[4], r[5]), __fadd_rn(r[6], r[7])));
}

// ---- row L2-normalize (numpy-exact) + emit bf16 hi/lo split planes ----
__global__ __launch_bounds__(256) void norm_rows_np_kernel(
    const float* __restrict__ src, float* __restrict__ dst,
    unsigned short* __restrict__ dsth, unsigned short* __restrict__ dstl)
{
    __shared__ float lds[NORM_ROWS_PER_BLK * D_DIM];
    __shared__ float nrm[NORM_ROWS_PER_BLK];
    const int tid = threadIdx.x;
    const size_t base = (size_t)blockIdx.x * NORM_ROWS_PER_BLK * D_DIM;

    #pragma unroll
    for (int i = 0; i < NORM_ROWS_PER_BLK; ++i)
        lds[i * 256 + tid] = src[base + i * 256 + tid];
    __syncthreads();

    if (tid < NORM_ROWS_PER_BLK) {
        const float* row = &lds[tid * D_DIM];
        const float tot = __fadd_rn(np_sumsq_128(row), np_sumsq_128(row + 128));
        const float n = (float)sqrt((double)tot);
        nrm[tid] = fmaxf(n, 1e-12f);
    }
    __syncthreads();

    #pragma unroll
    for (int i = 0; i < NORM_ROWS_PER_BLK; ++i) {
        const int e = i * 256 + tid;
        const float v = lds[e] / nrm[i];
        dst[base + e] = v;
        const unsigned short h = f2bf(v);
        dsth[base + e] = h;
        dstl[base + e] = f2bf(v - bf2f(h));
    }
}

// ---------------- split-bf16 MFMA GEMM: C[N,K] ~= A[N,D] * B[K,D]^T ----------------
// cos ~ Ah*Bh + Ah*Bl + Al*Bh (3 bf16 MFMAs, fp32 acc, pass order hh,hl,lh —
// bit-identical to the previously-passing kernel). |err| <= ~7e-5.
// 128x128 tile, BK=32, 4 waves (2x2), each wave 64x64 via 4x4 frags of 16x16x32.
//
// T4 counted-vmcnt pipeline (2-deep prefetch, raw s_barrier — NO full drain):
//   prologue: stage(T0), stage(T1)                      [16 loads in flight]
//   iter t:   vmcnt(8)  -> tile t landed, t+1 stays in flight
//             barrier + sched_barrier(0)   [pin reads AFTER barrier — s_barrier
//                                           is not a compiler memory fence]
//             16 ds_read_b128 frags; lgkmcnt(0)+sched_barrier(0)  [rule #18]
//             barrier + sched_barrier(0)   [pin refill AFTER all waves read b]
//             stage(b, T_{t+2})  -> refill b, covered by the 48 MFMAs below
//             setprio(1); 48 MFMA; setprio(0)                      [T5]
// LDS-hazard safety: each wave's global_load_lds writes ONLY its own slice;
// read-before-refill ordered by barrier#2; refill-before-reread by next
// iter's vmcnt(8)+barrier#1. T1: bijective XCD swizzle (4096 blocks % 8 == 0).
__global__ __launch_bounds__(256) void gemm_bf16x3_kernel(
    const unsigned short* __restrict__ Ah, const unsigned short* __restrict__ Al,
    const unsigned short* __restrict__ Bh, const unsigned short* __restrict__ Bl,
    float* __restrict__ C)
{
    __shared__ __align__(16) unsigned short smem[2 * 4 * 4096]; // dbuf x Ah|Al|Bh|Bl

    const int tid  = threadIdx.x;
    const int lane = tid & 63;
    const int wv   = tid >> 6;
    const int wr   = wv >> 1, wc = wv & 1;

    // T1: XCD-aware bijective swizzle of the 32x128 grid (nwg=4096, 4096%8==0)
    const int GX  = K_CODES / 128;                       // 32
    const int lin = blockIdx.y * GX + blockIdx.x;
    const int swz = (lin & 7) * (4096 / 8) + (lin >> 3);
    const int bm  = (swz / GX) * 128;
    const int bn  = (swz % GX) * 128;

    // staging geometry: 512 granules (16B) per plane = 2 parts x 256 threads
    const int og0 = tid, og1 = 256 + tid;
    const int row0 = og0 >> 2, row1 = og1 >> 2;
    const int g0 = (og0 & 3) ^ ((row0 >> 1) & 3);   // source granule for linear slot
    const int g1 = (og1 & 3) ^ ((row1 >> 1) & 3);
    const size_t asrc0 = (size_t)(bm + row0) * D_DIM + g0 * 8;
    const size_t asrc1 = (size_t)(bm + row1) * D_DIM + g1 * 8;
    const size_t bsrc0 = (size_t)(bn + row0) * D_DIM + g0 * 8;
    const size_t bsrc1 = (size_t)(bn + row1) * D_DIM + g1 * 8;

    // fragment read byte-offsets within a plane (swizzled)
    int aoff[4], boff[4];
    #pragma unroll
    for (int i = 0; i < 4; ++i) {
        const int ar = wr * 64 + i * 16 + (lane & 15);
        aoff[i] = ar * 64 + ((((lane >> 4) ^ ((ar >> 1) & 3)) & 3) << 4);
        const int br = wc * 64 + i * 16 + (lane & 15);
        boff[i] = br * 64 + ((((lane >> 4) ^ ((br >> 1) & 3)) & 3) << 4);
    }
    const char* sA = (const char*)smem;

    // stage one 32KB tile-set (all 4 planes) for K-step k0 into buffer buf.
    // Per wave: 8 global_load_lds (8 vmcnt events), each writing its OWN slice.
    auto stage = [&](int buf, int k0) {
        unsigned short* l0 = smem + buf * 16384 + wv * 512;          // part 0
        unsigned short* l1 = smem + buf * 16384 + 2048 + wv * 512;   // part 1
        gload16(Ah + asrc0 + k0, l0);
        gload16(Ah + asrc1 + k0, l1);
        gload16(Al + asrc0 + k0, l0 + 4096);
        gload16(Al + asrc1 + k0, l1 + 4096);
        gload16(Bh + bsrc0 + k0, l0 + 8192);
        gload16(Bh + bsrc1 + k0, l1 + 8192);
        gload16(Bl + bsrc0 + k0, l0 + 12288);
        gload16(Bl + bsrc1 + k0, l1 + 12288);
    };

    f32x4 acc[4][4] = {};

    stage(0, 0);                     // S0: 8 loads
    stage(1, 32);                    // S1: 8 loads (16 in flight)

    #pragma unroll
    for (int t = 0; t < 8; ++t) {
        const int b = t & 1;
        // tile t complete; leave tile t+1's 8 loads in flight (never drain to 0)
        if (t < 7) asm volatile("s_waitcnt vmcnt(8)" ::: "memory");
        else       asm volatile("s_waitcnt vmcnt(0)" ::: "memory");
        __builtin_amdgcn_s_barrier();            // buffer b visible to all waves
        __builtin_amdgcn_sched_barrier(0);       // pin reads after the barrier

        const char* base = sA + b * 32768;
        i32x4 ah[4], al[4], bh[4], bl[4];
        #pragma unroll
        for (int i = 0; i < 4; ++i) {
            ah[i] = *(const i32x4*)(base +         aoff[i]);
            al[i] = *(const i32x4*)(base +  8192 + aoff[i]);
            bh[i] = *(const i32x4*)(base + 16384 + boff[i]);
            bl[i] = *(const i32x4*)(base + 24576 + boff[i]);
        }
        asm volatile("s_waitcnt lgkmcnt(0)" ::: "memory");
        __builtin_amdgcn_sched_barrier(0);       // rule #18: pin MFMAs after reads
        __builtin_amdgcn_s_barrier();            // ALL waves done reading buffer b
        __builtin_amdgcn_sched_barrier(0);       // pin refill after the barrier

        if (t < 6) stage(b, (t + 2) * 32);       // refill b; covered by MFMAs below

        __builtin_amdgcn_s_setprio(1);           // T5
        #pragma unroll
        for (int i = 0; i < 4; ++i)
            #pragma unroll
            for (int j = 0; j < 4; ++j)
                MFMA(acc[i][j], ah[i], bh[j]);
        #pragma unroll
        for (int i = 0; i < 4; ++i)
            #pragma unroll
            for (int j = 0; j < 4; ++j)
                MFMA(acc[i][j], ah[i], bl[j]);
        #pragma unroll
        for (int i = 0; i < 4; ++i)
            #pragma unroll
            for (int j = 0; j < 4; ++j)
                MFMA(acc[i][j], al[i], bh[j]);
        __builtin_amdgcn_s_setprio(0);
    }
    asm volatile("s_nop 7\n\ts_nop 7\n\ts_nop 7");   // MFMA->VALU read fence

    // C/D layout: col = lane&15, row = (lane>>4)*4 + reg   [m89-verified]
    #pragma unroll
    for (int i = 0; i < 4; ++i) {
        const int r0 = bm + wr * 64 + i * 16 + ((lane >> 4) << 2);
        #pragma unroll
        for (int j = 0; j < 4; ++j) {
            const int c0 = bn + wc * 64 + j * 16 + (lane & 15);
            #pragma unroll
            for (int r = 0; r < 4; ++r)
                C[(size_t)(r0 + r) * K_CODES + c0] = acc[i][j][r];
        }
    }
}

// ---------------- per-row: windowed-exact argmin, softmax, gather ----------------
// P holds approximate cos (|err|<=~7e-5). Candidates with d_ap <= min+TAU are
// rescored with the EXACT sequential-fma fp32 dot (identical arithmetic to the
// original fp32 GEMM), first-index tie-break => idx bit-equivalent.
__global__ __launch_bounds__(256) void rowpass_kernel(
    float* __restrict__ P,            // [N,K] in: cos(approx), out: soft_probs
    const float* __restrict__ cbn,    // [K,D] normalized codebook (fp32)
    float* __restrict__ xq,           // [N,D] in: x_n, out: quantized
    float* __restrict__ idx_out,      // [N]
    float* __restrict__ counts,       // [K]
    float* __restrict__ rowloss)      // [N]
{
    const int row = blockIdx.x;
    const int t = threadIdx.x;
    float4* rp = (float4*)(P + (size_t)row * K_CODES);

    __shared__ float sf[4];
    __shared__ float sbd[4];
    __shared__ float s_x[D_DIM];
    __shared__ int   s_cnt;
    __shared__ int   s_cand[128];
    __shared__ float s_dex[128];
    __shared__ int   s_besti;

    float vals[16];
    #pragma unroll
    for (int j = 0; j < 4; ++j) {
        const float4 v = rp[j * 256 + t];
        vals[j * 4 + 0] = v.x; vals[j * 4 + 1] = v.y;
        vals[j * 4 + 2] = v.z; vals[j * 4 + 3] = v.w;
    }

    s_x[t] = xq[(size_t)row * D_DIM + t];
    if (t == 0) s_cnt = 0;

    // block max-cos (softmax) and approx min-dist
    float m = -1e30f, bd = 3.402823466e+38f;
    #pragma unroll
    for (int i = 0; i < 16; ++i) {
        m = fmaxf(m, vals[i]);
        bd = fminf(bd, 2.0f - 2.0f * vals[i]);
    }
    #pragma unroll
    for (int off = 32; off > 0; off >>= 1) {
        m  = fmaxf(m,  __shfl_down(m,  off));
        bd = fminf(bd, __shfl_down(bd, off));
    }
    if ((t & 63) == 0) { sf[t >> 6] = m; sbd[t >> 6] = bd; }
    __syncthreads();
    const float M  = fmaxf(fmaxf(sf[0], sf[1]), fmaxf(sf[2], sf[3]));
    const float fb = fminf(fminf(sbd[0], sbd[1]), fminf(sbd[2], sbd[3]));

    // ---- candidate window (TAU = 2^-7 >> 2 * max approx error) ----
    const float TAU = 0.0078125f;
    #pragma unroll
    for (int i = 0; i < 16; ++i) {
        const float d = 2.0f - 2.0f * vals[i];
        if (d <= fb + TAU) {
            const int p = atomicAdd(&s_cnt, 1);
            if (p < 128) s_cand[p] = ((i >> 2) * 256 + t) * 4 + (i & 3);
        }
    }
    __syncthreads();
    const int cnt = min(s_cnt, 128);
    if (cnt == 1) {
        if (t == 0) s_besti = s_cand[0];
    } else {
        if (t < cnt) {                 // exact rescore, sequential fma k=0..255
            const float* cb = cbn + (size_t)s_cand[t] * D_DIM;
            float acc = 0.0f;
            for (int k = 0; k < D_DIM; ++k) acc = fmaf(s_x[k], cb[k], acc);
            s_dex[t] = 2.0f - 2.0f * acc;
        }
        __syncthreads();
        if (t == 0) {                  // first-index tie-break
            float bdx = 3.402823466e+38f; int bii = 0x7fffffff;
            for (int c = 0; c < cnt; ++c) {
                const float d = s_dex[c]; const int ii = s_cand[c];
                if (d < bdx || (d == bdx && ii < bii)) { bdx = d; bii = ii; }
            }
            s_besti = bii;
        }
    }
    __syncthreads();
    const int besti = s_besti;

    // softmax: p_i = exp(20*(cos_i - M)) / sum
    float esum = 0.0f;
    #pragma unroll
    for (int i = 0; i < 16; ++i) {
        vals[i] = __expf(20.0f * (vals[i] - M));
        esum += vals[i];
    }
    #pragma unroll
    for (int off = 32; off > 0; off >>= 1) esum += __shfl_down(esum, off);
    __syncthreads();
    if ((t & 63) == 0) sf[t >> 6] = esum;
    __syncthreads();
    const float inv = 1.0f / (sf[0] + sf[1] + sf[2] + sf[3]);
    #pragma unroll
    for (int j = 0; j < 4; ++j) {
        rp[j * 256 + t] = make_float4(vals[j * 4 + 0] * inv, vals[j * 4 + 1] * inv,
                                      vals[j * 4 + 2] * inv, vals[j * 4 + 3] * inv);
    }

    // gather quantized row, per-row commitment loss
    const float q = cbn[(size_t)besti * D_DIM + t];
    xq[(size_t)row * D_DIM + t] = q;
    const float dd = q - s_x[t];
    float ls = dd * dd;
    #pragma unroll
    for (int off = 32; off > 0; off >>= 1) ls += __shfl_down(ls, off);
    __syncthreads();
    if ((t & 63) == 0) sf[t >> 6] = ls;
    __syncthreads();
    if (t == 0) {
        rowloss[row] = sf[0] + sf[1] + sf[2] + sf[3];
        idx_out[row] = (float)besti;
        atomicAdd(&counts[besti], 1.0f);
    }
}

// ---------------- finalize: vq_loss scalar + perplexity ----------------
__global__ __launch_bounds__(256) void finalize_kernel(
    const float* __restrict__ rowloss, const float* __restrict__ counts,
    float* __restrict__ out_loss, float* __restrict__ out_ppl)
{
    const int t = threadIdx.x;
    float s = 0.0f;
    for (int i = t; i < N_ROWS; i += 256) s += rowloss[i];
    float e = 0.0f;
    for (int i = t; i < K_CODES; i += 256) {
        const float avg = counts[i] * (1.0f / (float)N_ROWS);
        e += avg * logf(avg + 1e-10f);
    }
    #pragma unroll
    for (int off = 32; off > 0; off >>= 1) {
        s += __shfl_down(s, off);
        e += __shfl_down(e, off);
    }
    __shared__ float sf[4], se[4];
    if ((t & 63) == 0) { sf[t >> 6] = s; se[t >> 6] = e; }
    __syncthreads();
    if (t == 0) {
        out_loss[0] = 0.25f * (sf[0] + sf[1] + sf[2] + sf[3]) /
                      ((float)N_ROWS * (float)D_DIM);
        out_ppl[0] = expf(-(se[0] + se[1] + se[2] + se[3]));
    }
}

extern "C" void kernel_launch(void* const* d_in, const int* in_sizes, int n_in,
                              void* d_out, int out_size, void* d_ws, size_t ws_size,
                              hipStream_t stream) {
    const float* inputs   = (const float*)d_in[0];   // [N, D] raw
    const float* codebook = (const float*)d_in[1];   // [K, D] raw
    float* out = (float*)d_out;

    // output layout (flat, return order)
    float* vq_loss = out;                                   // 1
    float* quant   = out + 1;                               // N*D (also x_n scratch)
    float* probs   = quant + (size_t)N_ROWS * D_DIM;        // N*K
    float* ppl     = probs + (size_t)N_ROWS * K_CODES;      // 1
    float* idxout  = ppl + 1;                               // N

    // workspace layout (~25.3 MB)
    float* cbn     = (float*)d_ws;                          // K*D fp32
    float* counts  = cbn + (size_t)K_CODES * D_DIM;         // K
    float* rowloss = counts + K_CODES;                      // N
    unsigned short* Ah = (unsigned short*)(rowloss + N_ROWS);   // N*D bf16 hi
    unsigned short* Al = Ah + (size_t)N_ROWS * D_DIM;           // N*D bf16 lo
    unsigned short* Bh = Al + (size_t)N_ROWS * D_DIM;           // K*D bf16 hi
    unsigned short* Bl = Bh + (size_t)K_CODES * D_DIM;          // K*D bf16 lo

    hipMemsetAsync(counts, 0, K_CODES * sizeof(float), stream);
    norm_rows_np_kernel<<<K_CODES / NORM_ROWS_PER_BLK, 256, 0, stream>>>(codebook, cbn, Bh, Bl);
    norm_rows_np_kernel<<<N_ROWS / NORM_ROWS_PER_BLK, 256, 0, stream>>>(inputs, quant, Ah, Al);
    gemm_bf16x3_kernel<<<dim3(K_CODES / 128, N_ROWS / 128), 256, 0, stream>>>(Ah, Al, Bh, Bl, probs);
    rowpass_kernel<<<N_ROWS, 256, 0, stream>>>(probs, cbn, quant, idxout, counts, rowloss);
    finalize_kernel<<<1, 256, 0, stream>>>(rowloss, counts, vq_loss, ppl);
}

// Round 5
// 548.992 us; speedup vs baseline: 1.0024x; 1.0024x over previous
//
#include <hip/hip_runtime.h>
#include <cstdint>
#include <cstddef>

#define D_DIM 256
#define K_CODES 4096
#define N_ROWS 16384
#define NORM_ROWS_PER_BLK 32

typedef __attribute__((ext_vector_type(4))) int   i32x4;
typedef __attribute__((ext_vector_type(4))) float f32x4;

// ---- bf16 helpers (RNE) ----
__device__ __forceinline__ unsigned short f2bf(float x) {
    const unsigned int u = __float_as_uint(x);
    return (unsigned short)((u + 0x7fffu + ((u >> 16) & 1u)) >> 16);
}
__device__ __forceinline__ float bf2f(unsigned short h) {
    return __uint_as_float((unsigned int)h << 16);
}

// ---- async global->LDS, 16B per lane (dest is wave-uniform base + lane*16) ----
__device__ __forceinline__ void gload16(const unsigned short* g, unsigned short* l) {
    __builtin_amdgcn_global_load_lds(
        (const __attribute__((address_space(1))) void*)g,
        (__attribute__((address_space(3))) void*)l, 16, 0, 0);
}

// ---- inline-asm MFMA: D = A*B + D (gfx950, bf16 16x16x32, 4 VGPR frags) ----
#define MFMA(c, a, b) \
    asm volatile("v_mfma_f32_16x16x32_bf16 %0, %1, %2, %0" : "+v"(c) : "v"(a), "v"(b))

// ---- numpy-pairwise sum of squares of a 128-float block (fp32, no contraction) ----
__device__ __forceinline__ float np_sumsq_128(const float* __restrict__ a)
{
    float r[8];
    #pragma unroll
    for (int j = 0; j < 8; ++j) r[j] = __fmul_rn(a[j], a[j]);
    #pragma unroll
    for (int i = 8; i < 128; i += 8)
        #pragma unroll
        for (int j = 0; j < 8; ++j)
            r[j] = __fadd_rn(r[j], __fmul_rn(a[i + j], a[i + j]));
    return __fadd_rn(__fadd_rn(__fadd_rn(r[0], r[1]), __fadd_rn(r[2], r[3])),
                     __fadd_rn(__fadd_rn(r[4], r[5]), __fadd_rn(r[6], r[7])));
}

// ---- row L2-normalize (numpy-exact) + emit bf16 hi/lo split planes ----
__global__ __launch_bounds__(256) void norm_rows_np_kernel(
    const float* __restrict__ src, float* __restrict__ dst,
    unsigned short* __restrict__ dsth, unsigned short* __restrict__ dstl)
{
    __shared__ float lds[NORM_ROWS_PER_BLK * D_DIM];
    __shared__ float nrm[NORM_ROWS_PER_BLK];
    const int tid = threadIdx.x;
    const size_t base = (size_t)blockIdx.x * NORM_ROWS_PER_BLK * D_DIM;

    #pragma unroll
    for (int i = 0; i < NORM_ROWS_PER_BLK; ++i)
        lds[i * 256 + tid] = src[base + i * 256 + tid];
    __syncthreads();

    if (tid < NORM_ROWS_PER_BLK) {
        const float* row = &lds[tid * D_DIM];
        const float tot = __fadd_rn(np_sumsq_128(row), np_sumsq_128(row + 128));
        const float n = (float)sqrt((double)tot);
        nrm[tid] = fmaxf(n, 1e-12f);
    }
    __syncthreads();

    #pragma unroll
    for (int i = 0; i < NORM_ROWS_PER_BLK; ++i) {
        const int e = i * 256 + tid;
        const float v = lds[e] / nrm[i];
        dst[base + e] = v;
        const unsigned short h = f2bf(v);
        dsth[base + e] = h;
        dstl[base + e] = f2bf(v - bf2f(h));
    }
}

// ---------------- split-bf16 MFMA GEMM: C[N,K] ~= A[N,D] * B[K,D]^T ----------------
// cos ~ Ah*Bh + Ah*Bl + Al*Bh (3 bf16 MFMAs, fp32 acc, pass order hh,hl,lh —
// bit-identical accumulation to the previously-passing kernels). |err| <= ~7e-5.
// 128x128 tile, BK=32, 4 waves (2x2), each wave 64x64 via 4x4 frags of 16x16x32.
//
// Counted-vmcnt dbuf + COMPILER-SCHEDULED reads/MFMA interleave:
//   prologue: stage(T0), stage(T1)                      [16 loads in flight]
//   iter t:   vmcnt(8)  -> tile t landed, t+1 stays in flight (never drain mid-loop)
//             barrier + sched_barrier(0)   [pin reads after barrier; s_barrier is
//                                           not a compiler memory fence]
//             16 ds_read_b128 (plain C++) + 48 MFMA — compiler inserts
//             FINE-GRAINED lgkmcnt(N) waits (m97 behavior; no forced drain)
//             barrier + sched_barrier(0)   [all waves done reading b; reads are
//                                           complete here — consumed by MFMAs]
//             stage(b, T_{t+2})            [refill b; 2 phases to land]
// No setprio: T5 is null on lockstep 2-barrier structures (m190).
// T1: bijective XCD swizzle (4096 blocks % 8 == 0).
__global__ __launch_bounds__(256) void gemm_bf16x3_kernel(
    const unsigned short* __restrict__ Ah, const unsigned short* __restrict__ Al,
    const unsigned short* __restrict__ Bh, const unsigned short* __restrict__ Bl,
    float* __restrict__ C)
{
    __shared__ __align__(16) unsigned short smem[2 * 4 * 4096]; // dbuf x Ah|Al|Bh|Bl

    const int tid  = threadIdx.x;
    const int lane = tid & 63;
    const int wv   = tid >> 6;
    const int wr   = wv >> 1, wc = wv & 1;

    // T1: XCD-aware bijective swizzle of the 32x128 grid (nwg=4096, 4096%8==0)
    const int GX  = K_CODES / 128;                       // 32
    const int lin = blockIdx.y * GX + blockIdx.x;
    const int swz = (lin & 7) * (4096 / 8) + (lin >> 3);
    const int bm  = (swz / GX) * 128;
    const int bn  = (swz % GX) * 128;

    // staging geometry: 512 granules (16B) per plane = 2 parts x 256 threads
    const int og0 = tid, og1 = 256 + tid;
    const int row0 = og0 >> 2, row1 = og1 >> 2;
    const int g0 = (og0 & 3) ^ ((row0 >> 1) & 3);   // source granule for linear slot
    const int g1 = (og1 & 3) ^ ((row1 >> 1) & 3);
    const size_t asrc0 = (size_t)(bm + row0) * D_DIM + g0 * 8;
    const size_t asrc1 = (size_t)(bm + row1) * D_DIM + g1 * 8;
    const size_t bsrc0 = (size_t)(bn + row0) * D_DIM + g0 * 8;
    const size_t bsrc1 = (size_t)(bn + row1) * D_DIM + g1 * 8;

    // fragment read byte-offsets within a plane (swizzled)
    int aoff[4], boff[4];
    #pragma unroll
    for (int i = 0; i < 4; ++i) {
        const int ar = wr * 64 + i * 16 + (lane & 15);
        aoff[i] = ar * 64 + ((((lane >> 4) ^ ((ar >> 1) & 3)) & 3) << 4);
        const int br = wc * 64 + i * 16 + (lane & 15);
        boff[i] = br * 64 + ((((lane >> 4) ^ ((br >> 1) & 3)) & 3) << 4);
    }
    const char* sA = (const char*)smem;

    // stage one 32KB tile-set (all 4 planes) for K-step k0 into buffer buf.
    // Per wave: 8 global_load_lds (8 vmcnt events), each writing its OWN slice.
    auto stage = [&](int buf, int k0) {
        unsigned short* l0 = smem + buf * 16384 + wv * 512;          // part 0
        unsigned short* l1 = smem + buf * 16384 + 2048 + wv * 512;   // part 1
        gload16(Ah + asrc0 + k0, l0);
        gload16(Ah + asrc1 + k0, l1);
        gload16(Al + asrc0 + k0, l0 + 4096);
        gload16(Al + asrc1 + k0, l1 + 4096);
        gload16(Bh + bsrc0 + k0, l0 + 8192);
        gload16(Bh + bsrc1 + k0, l1 + 8192);
        gload16(Bl + bsrc0 + k0, l0 + 12288);
        gload16(Bl + bsrc1 + k0, l1 + 12288);
    };

    f32x4 acc[4][4] = {};

    stage(0, 0);                     // S0: 8 loads
    stage(1, 32);                    // S1: 8 loads (16 in flight)

    #pragma unroll
    for (int t = 0; t < 8; ++t) {
        const int b = t & 1;
        // tile t complete; leave tile t+1's 8 loads in flight (never drain to 0)
        if (t < 7) asm volatile("s_waitcnt vmcnt(8)" ::: "memory");
        else       asm volatile("s_waitcnt vmcnt(0)" ::: "memory");
        __builtin_amdgcn_s_barrier();            // buffer b visible to all waves
        __builtin_amdgcn_sched_barrier(0);       // pin reads after the barrier

        const char* base = sA + b * 32768;
        i32x4 ah[4], al[4], bh[4], bl[4];
        #pragma unroll
        for (int i = 0; i < 4; ++i) {
            ah[i] = *(const i32x4*)(base +         aoff[i]);
            al[i] = *(const i32x4*)(base +  8192 + aoff[i]);
            bh[i] = *(const i32x4*)(base + 16384 + boff[i]);
            bl[i] = *(const i32x4*)(base + 24576 + boff[i]);
        }
        // MFMAs: compiler interleaves with the reads above via fine lgkmcnt(N)
        #pragma unroll
        for (int i = 0; i < 4; ++i)
            #pragma unroll
            for (int j = 0; j < 4; ++j)
                MFMA(acc[i][j], ah[i], bh[j]);
        #pragma unroll
        for (int i = 0; i < 4; ++i)
            #pragma unroll
            for (int j = 0; j < 4; ++j)
                MFMA(acc[i][j], ah[i], bl[j]);
        #pragma unroll
        for (int i = 0; i < 4; ++i)
            #pragma unroll
            for (int j = 0; j < 4; ++j)
                MFMA(acc[i][j], al[i], bh[j]);

        __builtin_amdgcn_sched_barrier(0);       // keep read+MFMA cluster above
        __builtin_amdgcn_s_barrier();            // ALL waves done reading buffer b
        __builtin_amdgcn_sched_barrier(0);       // pin refill after the barrier

        if (t < 6) stage(b, (t + 2) * 32);       // refill b; lands during t+1
    }
    asm volatile("s_nop 7\n\ts_nop 7\n\ts_nop 7");   // MFMA->VALU read fence

    // C/D layout: col = lane&15, row = (lane>>4)*4 + reg   [m89-verified]
    #pragma unroll
    for (int i = 0; i < 4; ++i) {
        const int r0 = bm + wr * 64 + i * 16 + ((lane >> 4) << 2);
        #pragma unroll
        for (int j = 0; j < 4; ++j) {
            const int c0 = bn + wc * 64 + j * 16 + (lane & 15);
            #pragma unroll
            for (int r = 0; r < 4; ++r)
                C[(size_t)(r0 + r) * K_CODES + c0] = acc[i][j][r];
        }
    }
}

// ---------------- per-row pass, ONE WAVE PER ROW ----------------
// 4 rows per 256-thread block; all reductions are wave-level __shfl trees —
// ZERO block barriers. Per-wave LDS (s_x, s_cand, s_cnt) relies on same-wave
// in-order LDS execution. Bit-exactness vs previous passing version:
//   * M (max cos) / fb (min dist): fmax/fmin are order-independent -> identical
//   * candidate set: same per-element test vs identical fb -> identical
//   * rescore: identical serial-fma dot + lexicographic (d, idx) min, which
//     equals first-index tie-break -> besti BIT-IDENTICAL -> idx/quant/counts/
//     perplexity bit-identical
//   * esum / rowloss: summation grouping changes (~1 ulp) — tolerance-checked
__global__ __launch_bounds__(256) void rowpass_kernel(
    float* __restrict__ P,            // [N,K] in: cos(approx), out: soft_probs
    const float* __restrict__ cbn,    // [K,D] normalized codebook (fp32)
    float* __restrict__ xq,           // [N,D] in: x_n, out: quantized
    float* __restrict__ idx_out,      // [N]
    float* __restrict__ counts,       // [K]
    float* __restrict__ rowloss)      // [N]
{
    const int w = threadIdx.x >> 6;       // wave 0..3
    const int l = threadIdx.x & 63;       // lane
    const int row = blockIdx.x * 4 + w;
    float4* rp = (float4*)(P + (size_t)row * K_CODES);

    __shared__ float s_x[4][D_DIM];
    __shared__ int   s_cand[4][128];
    __shared__ int   s_cnt[4];

    // load full row: 16 coalesced float4 per lane (16 loads in flight)
    float vals[64];
    #pragma unroll
    for (int j = 0; j < 16; ++j) {
        const float4 v = rp[j * 64 + l];
        vals[j * 4 + 0] = v.x; vals[j * 4 + 1] = v.y;
        vals[j * 4 + 2] = v.z; vals[j * 4 + 3] = v.w;
    }
    // x_n row -> LDS (needed serially by the rescore) + registers (loss)
    const float4 xv4 = *(const float4*)&xq[(size_t)row * D_DIM + l * 4];
    *(float4*)&s_x[w][l * 4] = xv4;
    if (l == 0) s_cnt[w] = 0;

    // per-row max cos (softmax) and min approx dist — wave shuffle reduce
    float m = -1e30f, bd = 3.402823466e+38f;
    #pragma unroll
    for (int i = 0; i < 64; ++i) {
        m  = fmaxf(m, vals[i]);
        bd = fminf(bd, 2.0f - 2.0f * vals[i]);
    }
    #pragma unroll
    for (int off = 32; off > 0; off >>= 1) {
        m  = fmaxf(m,  __shfl_down(m,  off));
        bd = fminf(bd, __shfl_down(bd, off));
    }
    const float M  = __shfl(m, 0);
    const float fb = __shfl(bd, 0);

    // ---- candidate window (TAU = 2^-7 >> 2 * max approx error) ----
    const float TAU = 0.0078125f;
    #pragma unroll
    for (int i = 0; i < 64; ++i) {
        const float d = 2.0f - 2.0f * vals[i];
        if (d <= fb + TAU) {
            const int p = atomicAdd(&s_cnt[w], 1);
            if (p < 128) s_cand[w][p] = ((i >> 2) * 64 + l) * 4 + (i & 3);
        }
    }
    const int cnt = min(s_cnt[w], 128);   // same-wave LDS pipe order: visible

    int besti;
    if (cnt == 1) {                       // wave-uniform branch
        besti = s_cand[w][0];
    } else {
        // exact rescore: sequential fma k=0..255 (identical arithmetic to the
        // original fp32 GEMM); lanes take candidates in parallel
        float bdx = 3.402823466e+38f; int bii = 0x7fffffff;
        for (int c = l; c < cnt; c += 64) {
            const int ii = s_cand[w][c];
            const float* cb = cbn + (size_t)ii * D_DIM;
            float a = 0.0f;
            for (int k = 0; k < D_DIM; ++k) a = fmaf(s_x[w][k], cb[k], a);
            const float d = 2.0f - 2.0f * a;
            if (d < bdx || (d == bdx && ii < bii)) { bdx = d; bii = ii; }
        }
        #pragma unroll
        for (int off = 32; off > 0; off >>= 1) {
            const float od = __shfl_down(bdx, off);
            const int   oi = __shfl_down(bii, off);
            if (od < bdx || (od == bdx && oi < bii)) { bdx = od; bii = oi; }
        }
        besti = __shfl(bii, 0);
    }

    // softmax: p_i = exp(20*(cos_i - M)) / sum   (TEMP=0.1, dist=2-2cos)
    float esum = 0.0f;
    #pragma unroll
    for (int i = 0; i < 64; ++i) {
        vals[i] = __expf(20.0f * (vals[i] - M));
        esum += vals[i];
    }
    #pragma unroll
    for (int off = 32; off > 0; off >>= 1) esum += __shfl_down(esum, off);
    const float inv = 1.0f / __shfl(esum, 0);
    #pragma unroll
    for (int j = 0; j < 16; ++j) {
        rp[j * 64 + l] = make_float4(vals[j * 4 + 0] * inv, vals[j * 4 + 1] * inv,
                                     vals[j * 4 + 2] * inv, vals[j * 4 + 3] * inv);
    }

    // gather quantized row + per-row commitment loss
    const float4 q4 = *(const float4*)&cbn[(size_t)besti * D_DIM + l * 4];
    *(float4*)&xq[(size_t)row * D_DIM + l * 4] = q4;
    const float d0 = q4.x - xv4.x, d1 = q4.y - xv4.y;
    const float d2 = q4.z - xv4.z, d3 = q4.w - xv4.w;
    float ls = d0 * d0 + d1 * d1 + d2 * d2 + d3 * d3;
    #pragma unroll
    for (int off = 32; off > 0; off >>= 1) ls += __shfl_down(ls, off);
    if (l == 0) {
        rowloss[row] = ls;
        idx_out[row] = (float)besti;
        atomicAdd(&counts[besti], 1.0f);
    }
}

// ---------------- finalize: vq_loss scalar + perplexity ----------------
__global__ __launch_bounds__(256) void finalize_kernel(
    const float* __restrict__ rowloss, const float* __restrict__ counts,
    float* __restrict__ out_loss, float* __restrict__ out_ppl)
{
    const int t = threadIdx.x;
    float s = 0.0f;
    for (int i = t; i < N_ROWS; i += 256) s += rowloss[i];
    float e = 0.0f;
    for (int i = t; i < K_CODES; i += 256) {
        const float avg = counts[i] * (1.0f / (float)N_ROWS);
        e += avg * logf(avg + 1e-10f);
    }
    #pragma unroll
    for (int off = 32; off > 0; off >>= 1) {
        s += __shfl_down(s, off);
        e += __shfl_down(e, off);
    }
    __shared__ float sf[4], se[4];
    if ((t & 63) == 0) { sf[t >> 6] = s; se[t >> 6] = e; }
    __syncthreads();
    if (t == 0) {
        out_loss[0] = 0.25f * (sf[0] + sf[1] + sf[2] + sf[3]) /
                      ((float)N_ROWS * (float)D_DIM);
        out_ppl[0] = expf(-(se[0] + se[1] + se[2] + se[3]));
    }
}

extern "C" void kernel_launch(void* const* d_in, const int* in_sizes, int n_in,
                              void* d_out, int out_size, void* d_ws, size_t ws_size,
                              hipStream_t stream) {
    const float* inputs   = (const float*)d_in[0];   // [N, D] raw
    const float* codebook = (const float*)d_in[1];   // [K, D] raw
    float* out = (float*)d_out;

    // output layout (flat, return order)
    float* vq_loss = out;                                   // 1
    float* quant   = out + 1;                               // N*D (also x_n scratch)
    float* probs   = quant + (size_t)N_ROWS * D_DIM;        // N*K
    float* ppl     = probs + (size_t)N_ROWS * K_CODES;      // 1
    float* idxout  = ppl + 1;                               // N

    // workspace layout (~25.3 MB)
    float* cbn     = (float*)d_ws;                          // K*D fp32
    float* counts  = cbn + (size_t)K_CODES * D_DIM;         // K
    float* rowloss = counts + K_CODES;                      // N
    unsigned short* Ah = (unsigned short*)(rowloss + N_ROWS);   // N*D bf16 hi
    unsigned short* Al = Ah + (size_t)N_ROWS * D_DIM;           // N*D bf16 lo
    unsigned short* Bh = Al + (size_t)N_ROWS * D_DIM;           // K*D bf16 hi
    unsigned short* Bl = Bh + (size_t)K_CODES * D_DIM;          // K*D bf16 lo

    hipMemsetAsync(counts, 0, K_CODES * sizeof(float), stream);
    norm_rows_np_kernel<<<K_CODES / NORM_ROWS_PER_BLK, 256, 0, stream>>>(codebook, cbn, Bh, Bl);
    norm_rows_np_kernel<<<N_ROWS / NORM_ROWS_PER_BLK, 256, 0, stream>>>(inputs, quant, Ah, Al);
    gemm_bf16x3_kernel<<<dim3(K_CODES / 128, N_ROWS / 128), 256, 0, stream>>>(Ah, Al, Bh, Bl, probs);
    rowpass_kernel<<<N_ROWS / 4, 256, 0, stream>>>(probs, cbn, quant, idxout, counts, rowloss);
    finalize_kernel<<<1, 256, 0, stream>>>(rowloss, counts, vq_loss, ppl);
}

// Round 6
// 541.005 us; speedup vs baseline: 1.0172x; 1.0148x over previous
//
#include <hip/hip_runtime.h>
#include <cstdint>
#include <cstddef>

#define D_DIM 256
#define K_CODES 4096
#define N_ROWS 16384
#define NORM_ROWS_PER_BLK 32

typedef __attribute__((ext_vector_type(4))) int   i32x4;
typedef __attribute__((ext_vector_type(4))) float f32x4;

// ---- bf16 helpers (RNE) ----
__device__ __forceinline__ unsigned short f2bf(float x) {
    const unsigned int u = __float_as_uint(x);
    return (unsigned short)((u + 0x7fffu + ((u >> 16) & 1u)) >> 16);
}
__device__ __forceinline__ float bf2f(unsigned short h) {
    return __uint_as_float((unsigned int)h << 16);
}

// ---- async global->LDS, 16B per lane (dest is wave-uniform base + lane*16) ----
__device__ __forceinline__ void gload16(const unsigned short* g, unsigned short* l) {
    __builtin_amdgcn_global_load_lds(
        (const __attribute__((address_space(1))) void*)g,
        (__attribute__((address_space(3))) void*)l, 16, 0, 0);
}

// ---- inline-asm MFMA: D = A*B + D (gfx950, bf16 16x16x32, 4 VGPR frags) ----
#define MFMA(c, a, b) \
    asm volatile("v_mfma_f32_16x16x32_bf16 %0, %1, %2, %0" : "+v"(c) : "v"(a), "v"(b))

// ---- numpy-pairwise sum of squares of a 128-float block (fp32, no contraction) ----
__device__ __forceinline__ float np_sumsq_128(const float* __restrict__ a)
{
    float r[8];
    #pragma unroll
    for (int j = 0; j < 8; ++j) r[j] = __fmul_rn(a[j], a[j]);
    #pragma unroll
    for (int i = 8; i < 128; i += 8)
        #pragma unroll
        for (int j = 0; j < 8; ++j)
            r[j] = __fadd_rn(r[j], __fmul_rn(a[i + j], a[i + j]));
    return __fadd_rn(__fadd_rn(__fadd_rn(r[0], r[1]), __fadd_rn(r[2], r[3])),
                     __fadd_rn(__fadd_rn(r[4], r[5]), __fadd_rn(r[6], r[7])));
}

// ---- row L2-normalize (numpy-exact) + emit bf16 hi/lo split planes ----
__global__ __launch_bounds__(256) void norm_rows_np_kernel(
    const float* __restrict__ src, float* __restrict__ dst,
    unsigned short* __restrict__ dsth, unsigned short* __restrict__ dstl)
{
    __shared__ float lds[NORM_ROWS_PER_BLK * D_DIM];
    __shared__ float nrm[NORM_ROWS_PER_BLK];
    const int tid = threadIdx.x;
    const size_t base = (size_t)blockIdx.x * NORM_ROWS_PER_BLK * D_DIM;

    #pragma unroll
    for (int i = 0; i < NORM_ROWS_PER_BLK; ++i)
        lds[i * 256 + tid] = src[base + i * 256 + tid];
    __syncthreads();

    if (tid < NORM_ROWS_PER_BLK) {
        const float* row = &lds[tid * D_DIM];
        const float tot = __fadd_rn(np_sumsq_128(row), np_sumsq_128(row + 128));
        const float n = (float)sqrt((double)tot);
        nrm[tid] = fmaxf(n, 1e-12f);
    }
    __syncthreads();

    #pragma unroll
    for (int i = 0; i < NORM_ROWS_PER_BLK; ++i) {
        const int e = i * 256 + tid;
        const float v = lds[e] / nrm[i];
        dst[base + e] = v;
        const unsigned short h = f2bf(v);
        dsth[base + e] = h;
        dstl[base + e] = f2bf(v - bf2f(h));
    }
}

// ================= 8-phase 256x256 split-bf16 GEMM, virtual K=768 =================
// C[N,K] ~= Ah*Bh^T + Ah*Bl^T + Al*Bh^T, expressed as ONE bf16 GEMM over
// K=768: K-tiles 0-3 use (Ah,Bh), 4-7 (Ah,Bl), 8-11 (Al,Bh). Same FLOPs and
// pass order as the verified kernel; accumulation re-association ~1e-6 on cos.
//
// Geometry (m201 template): BM=BN=256, BK=64, 8 waves (2Mx4N), 512 threads.
// Per-wave output 128x64 (8x4 frags of 16x16). LDS 128 KB: 2 buf x (A[2 khalf]
// [256 rows][32 k] + B same). 4 phases per K-tile:
//   P1: kh0, frags m0-3 + all B      P2: kh0, m4-7 (B held in regs)
//   P3: kh1, m0-3 + B                P4: kh1, m4-7
// Each phase: [vmcnt] barrier schedb | ds_reads | 1 half-region stage |
//             lgkmcnt(0) schedb | setprio(1) 16 MFMA setprio(0).
//
// STAGE ledger (2 loads per stage; pairs in issue order — verified drain math):
//   prologue: A0k0 B0k0 A0k1 B0k1 A1k0 B1k0                      (12 loads)
//   tile T:   P1 stages A(T+1)k1, P2 B(T+1)k1, P3 A(T+2)k0, P4 B(T+2)k0
//   waits:    P1 vmcnt(8) [drains A(T)k0,B(T)k0], P3 vmcnt(8) [A(T)k1,B(T)k1]
//   tail:     T=11: P1 vmcnt(4), P3 vmcnt(0); stages auto-skip at index>=12
// WRITE-SAFETY: a stage's region had its last ds_read >=1 barrier before the
// stage ISSUES (P1->prev tile P4; P2->prev P3; P3->this P2; P4->this P1, B is
// read only in P1/P3), and writes land no earlier than issue. READ-SAFETY:
// per-wave vmcnt before barrier => all waves' stages landed before any read.
//
// T2: LDS slot-swizzle phys = logical ^ (row&3), applied on the GLOBAL source
// (gload_lds dest must stay linear) and on the ds_read address -> bank-uniform
// (8 accesses/bank = b128 floor). T1: bijective XCD swizzle (1024 blocks).
__global__ __launch_bounds__(512, 2) void gemm_bf16x3_kernel(
    const unsigned short* __restrict__ Ah, const unsigned short* __restrict__ Al,
    const unsigned short* __restrict__ Bh, const unsigned short* __restrict__ Bl,
    float* __restrict__ C)
{
    __shared__ __align__(16) unsigned short smem[65536];   // 128 KB

    const int tid  = threadIdx.x;
    const int lane = tid & 63;
    const int wv   = tid >> 6;          // 0..7
    const int wr   = wv >> 2;           // 0..1  (M)
    const int wc   = wv & 3;            // 0..3  (N)

    // T1: XCD swizzle of the 16x64 grid (nwg=1024, 1024%8==0)
    const int GX  = K_CODES / 256;                      // 16
    const int lin = blockIdx.y * GX + blockIdx.x;
    const int swz = (lin & 7) * (1024 / 8) + (lin >> 3);
    const int bm  = (swz / GX) * 256;
    const int bn  = (swz % GX) * 256;

    // staging geometry: region = [256 rows][4 slots of 8 bf16]; 16 chunks of
    // 1KB; wave wv owns chunks 2wv, 2wv+1. dest (row, phys=lane&3) fetches
    // global logical slot phys ^ (row&3).
    const int srow0 = wv * 32 + (lane >> 2);
    const int srow1 = srow0 + 16;
    const int sl    = (lane & 3) ^ ((lane >> 2) & 3);   // same for both rows

    #define STAGE_A(T, h)                                                        \
        do { const unsigned short* pl_ = ((T) < 8) ? Ah : Al;                    \
             unsigned short* d_ = smem + ((T) & 1) * 32768 + (h) * 8192;         \
             const int kb_ = ((T) & 3) * 64 + (h) * 32 + sl * 8;                 \
             gload16(pl_ + (size_t)(bm + srow0) * 256 + kb_, d_ + (wv*2+0)*512); \
             gload16(pl_ + (size_t)(bm + srow1) * 256 + kb_, d_ + (wv*2+1)*512); \
        } while (0)
    #define STAGE_B(T, h)                                                        \
        do { const unsigned short* pl_ = ((T) < 4) ? Bh : (((T) < 8) ? Bl : Bh); \
             unsigned short* d_ = smem + ((T) & 1) * 32768 + 16384 + (h) * 8192; \
             const int kb_ = ((T) & 3) * 64 + (h) * 32 + sl * 8;                 \
             gload16(pl_ + (size_t)(bn + srow0) * 256 + kb_, d_ + (wv*2+0)*512); \
             gload16(pl_ + (size_t)(bn + srow1) * 256 + kb_, d_ + (wv*2+1)*512); \
        } while (0)

    // fragment read byte-offsets (within a [buf][khalf] region pair)
    const int fr   = lane & 15;
    const int phys = ((lane >> 4) ^ (lane & 3));
    int aoff[8], boff[4];
    #pragma unroll
    for (int mi = 0; mi < 8; ++mi)
        aoff[mi] = (wr * 128 + mi * 16 + fr) * 64 + phys * 16;
    #pragma unroll
    for (int ni = 0; ni < 4; ++ni)
        boff[ni] = 32768 + (wc * 64 + ni * 16 + fr) * 64 + phys * 16;
    const char* sA = (const char*)smem;

    f32x4 acc[8][4] = {};

    // prologue: tile0 full + tile1 khalf0  (6 stages, 12 loads in flight)
    STAGE_A(0, 0); STAGE_B(0, 0); STAGE_A(0, 1); STAGE_B(0, 1);
    STAGE_A(1, 0); STAGE_B(1, 0);

    #pragma unroll 2
    for (int T = 0; T < 12; ++T) {
        const int buf = T & 1;
        const char* base0 = sA + buf * 65536;          // khalf 0
        const char* base1 = base0 + 16384;             // khalf 1
        i32x4 a[4], bfr[4];

        // ---------------- P1: kh0, m0-3 ----------------
        if (T < 11) asm volatile("s_waitcnt vmcnt(8)" ::: "memory");
        else        asm volatile("s_waitcnt vmcnt(4)" ::: "memory");
        __builtin_amdgcn_s_barrier();
        __builtin_amdgcn_sched_barrier(0);
        #pragma unroll
        for (int ni = 0; ni < 4; ++ni) bfr[ni] = *(const i32x4*)(base0 + boff[ni]);
        #pragma unroll
        for (int mi = 0; mi < 4; ++mi) a[mi] = *(const i32x4*)(base0 + aoff[mi]);
        if (T + 1 < 12) STAGE_A(T + 1, 1);
        asm volatile("s_waitcnt lgkmcnt(0)" ::: "memory");
        __builtin_amdgcn_sched_barrier(0);
        __builtin_amdgcn_s_setprio(1);
        #pragma unroll
        for (int mi = 0; mi < 4; ++mi)
            #pragma unroll
            for (int ni = 0; ni < 4; ++ni) MFMA(acc[mi][ni], a[mi], bfr[ni]);
        __builtin_amdgcn_s_setprio(0);

        // ---------------- P2: kh0, m4-7 ----------------
        __builtin_amdgcn_s_barrier();
        __builtin_amdgcn_sched_barrier(0);
        #pragma unroll
        for (int mi = 0; mi < 4; ++mi) a[mi] = *(const i32x4*)(base0 + aoff[4 + mi]);
        if (T + 1 < 12) STAGE_B(T + 1, 1);
        asm volatile("s_waitcnt lgkmcnt(0)" ::: "memory");
        __builtin_amdgcn_sched_barrier(0);
        __builtin_amdgcn_s_setprio(1);
        #pragma unroll
        for (int mi = 0; mi < 4; ++mi)
            #pragma unroll
            for (int ni = 0; ni < 4; ++ni) MFMA(acc[4 + mi][ni], a[mi], bfr[ni]);
        __builtin_amdgcn_s_setprio(0);

        // ---------------- P3: kh1, m0-3 ----------------
        if (T < 11) asm volatile("s_waitcnt vmcnt(8)" ::: "memory");
        else        asm volatile("s_waitcnt vmcnt(0)" ::: "memory");
        __builtin_amdgcn_s_barrier();
        __builtin_amdgcn_sched_barrier(0);
        #pragma unroll
        for (int ni = 0; ni < 4; ++ni) bfr[ni] = *(const i32x4*)(base1 + boff[ni]);
        #pragma unroll
        for (int mi = 0; mi < 4; ++mi) a[mi] = *(const i32x4*)(base1 + aoff[mi]);
        if (T + 2 < 12) STAGE_A(T + 2, 0);
        asm volatile("s_waitcnt lgkmcnt(0)" ::: "memory");
        __builtin_amdgcn_sched_barrier(0);
        __builtin_amdgcn_s_setprio(1);
        #pragma unroll
        for (int mi = 0; mi < 4; ++mi)
            #pragma unroll
            for (int ni = 0; ni < 4; ++ni) MFMA(acc[mi][ni], a[mi], bfr[ni]);
        __builtin_amdgcn_s_setprio(0);

        // ---------------- P4: kh1, m4-7 ----------------
        __builtin_amdgcn_s_barrier();
        __builtin_amdgcn_sched_barrier(0);
        #pragma unroll
        for (int mi = 0; mi < 4; ++mi) a[mi] = *(const i32x4*)(base1 + aoff[4 + mi]);
        if (T + 2 < 12) STAGE_B(T + 2, 0);
        asm volatile("s_waitcnt lgkmcnt(0)" ::: "memory");
        __builtin_amdgcn_sched_barrier(0);
        __builtin_amdgcn_s_setprio(1);
        #pragma unroll
        for (int mi = 0; mi < 4; ++mi)
            #pragma unroll
            for (int ni = 0; ni < 4; ++ni) MFMA(acc[4 + mi][ni], a[mi], bfr[ni]);
        __builtin_amdgcn_s_setprio(0);
    }
    asm volatile("s_nop 7\n\ts_nop 7\n\ts_nop 7");   // MFMA->VALU read fence

    // C/D layout: col = lane&15, row = (lane>>4)*4 + reg   [m89-verified]
    #pragma unroll
    for (int mi = 0; mi < 8; ++mi) {
        const int r0 = bm + wr * 128 + mi * 16 + ((lane >> 4) << 2);
        #pragma unroll
        for (int ni = 0; ni < 4; ++ni) {
            const int c0 = bn + wc * 64 + ni * 16 + (lane & 15);
            #pragma unroll
            for (int r = 0; r < 4; ++r)
                C[(size_t)(r0 + r) * K_CODES + c0] = acc[mi][ni][r];
        }
    }
    #undef STAGE_A
    #undef STAGE_B
}

// ---------------- per-row pass, ONE WAVE PER ROW (round-5 verified) ----------------
__global__ __launch_bounds__(256) void rowpass_kernel(
    float* __restrict__ P,            // [N,K] in: cos(approx), out: soft_probs
    const float* __restrict__ cbn,    // [K,D] normalized codebook (fp32)
    float* __restrict__ xq,           // [N,D] in: x_n, out: quantized
    float* __restrict__ idx_out,      // [N]
    float* __restrict__ counts,       // [K]
    float* __restrict__ rowloss)      // [N]
{
    const int w = threadIdx.x >> 6;       // wave 0..3
    const int l = threadIdx.x & 63;       // lane
    const int row = blockIdx.x * 4 + w;
    float4* rp = (float4*)(P + (size_t)row * K_CODES);

    __shared__ float s_x[4][D_DIM];
    __shared__ int   s_cand[4][128];
    __shared__ int   s_cnt[4];

    float vals[64];
    #pragma unroll
    for (int j = 0; j < 16; ++j) {
        const float4 v = rp[j * 64 + l];
        vals[j * 4 + 0] = v.x; vals[j * 4 + 1] = v.y;
        vals[j * 4 + 2] = v.z; vals[j * 4 + 3] = v.w;
    }
    const float4 xv4 = *(const float4*)&xq[(size_t)row * D_DIM + l * 4];
    *(float4*)&s_x[w][l * 4] = xv4;
    if (l == 0) s_cnt[w] = 0;

    float m = -1e30f, bd = 3.402823466e+38f;
    #pragma unroll
    for (int i = 0; i < 64; ++i) {
        m  = fmaxf(m, vals[i]);
        bd = fminf(bd, 2.0f - 2.0f * vals[i]);
    }
    #pragma unroll
    for (int off = 32; off > 0; off >>= 1) {
        m  = fmaxf(m,  __shfl_down(m,  off));
        bd = fminf(bd, __shfl_down(bd, off));
    }
    const float M  = __shfl(m, 0);
    const float fb = __shfl(bd, 0);

    const float TAU = 0.0078125f;
    #pragma unroll
    for (int i = 0; i < 64; ++i) {
        const float d = 2.0f - 2.0f * vals[i];
        if (d <= fb + TAU) {
            const int p = atomicAdd(&s_cnt[w], 1);
            if (p < 128) s_cand[w][p] = ((i >> 2) * 64 + l) * 4 + (i & 3);
        }
    }
    const int cnt = min(s_cnt[w], 128);

    int besti;
    if (cnt == 1) {
        besti = s_cand[w][0];
    } else {
        float bdx = 3.402823466e+38f; int bii = 0x7fffffff;
        for (int c = l; c < cnt; c += 64) {
            const int ii = s_cand[w][c];
            const float* cb = cbn + (size_t)ii * D_DIM;
            float a = 0.0f;
            for (int k = 0; k < D_DIM; ++k) a = fmaf(s_x[w][k], cb[k], a);
            const float d = 2.0f - 2.0f * a;
            if (d < bdx || (d == bdx && ii < bii)) { bdx = d; bii = ii; }
        }
        #pragma unroll
        for (int off = 32; off > 0; off >>= 1) {
            const float od = __shfl_down(bdx, off);
            const int   oi = __shfl_down(bii, off);
            if (od < bdx || (od == bdx && oi < bii)) { bdx = od; bii = oi; }
        }
        besti = __shfl(bii, 0);
    }

    float esum = 0.0f;
    #pragma unroll
    for (int i = 0; i < 64; ++i) {
        vals[i] = __expf(20.0f * (vals[i] - M));
        esum += vals[i];
    }
    #pragma unroll
    for (int off = 32; off > 0; off >>= 1) esum += __shfl_down(esum, off);
    const float inv = 1.0f / __shfl(esum, 0);
    #pragma unroll
    for (int j = 0; j < 16; ++j) {
        rp[j * 64 + l] = make_float4(vals[j * 4 + 0] * inv, vals[j * 4 + 1] * inv,
                                     vals[j * 4 + 2] * inv, vals[j * 4 + 3] * inv);
    }

    const float4 q4 = *(const float4*)&cbn[(size_t)besti * D_DIM + l * 4];
    *(float4*)&xq[(size_t)row * D_DIM + l * 4] = q4;
    const float d0 = q4.x - xv4.x, d1 = q4.y - xv4.y;
    const float d2 = q4.z - xv4.z, d3 = q4.w - xv4.w;
    float ls = d0 * d0 + d1 * d1 + d2 * d2 + d3 * d3;
    #pragma unroll
    for (int off = 32; off > 0; off >>= 1) ls += __shfl_down(ls, off);
    if (l == 0) {
        rowloss[row] = ls;
        idx_out[row] = (float)besti;
        atomicAdd(&counts[besti], 1.0f);
    }
}

// ---------------- finalize: vq_loss scalar + perplexity ----------------
__global__ __launch_bounds__(256) void finalize_kernel(
    const float* __restrict__ rowloss, const float* __restrict__ counts,
    float* __restrict__ out_loss, float* __restrict__ out_ppl)
{
    const int t = threadIdx.x;
    float s = 0.0f;
    for (int i = t; i < N_ROWS; i += 256) s += rowloss[i];
    float e = 0.0f;
    for (int i = t; i < K_CODES; i += 256) {
        const float avg = counts[i] * (1.0f / (float)N_ROWS);
        e += avg * logf(avg + 1e-10f);
    }
    #pragma unroll
    for (int off = 32; off > 0; off >>= 1) {
        s += __shfl_down(s, off);
        e += __shfl_down(e, off);
    }
    __shared__ float sf[4], se[4];
    if ((t & 63) == 0) { sf[t >> 6] = s; se[t >> 6] = e; }
    __syncthreads();
    if (t == 0) {
        out_loss[0] = 0.25f * (sf[0] + sf[1] + sf[2] + sf[3]) /
                      ((float)N_ROWS * (float)D_DIM);
        out_ppl[0] = expf(-(se[0] + se[1] + se[2] + se[3]));
    }
}

extern "C" void kernel_launch(void* const* d_in, const int* in_sizes, int n_in,
                              void* d_out, int out_size, void* d_ws, size_t ws_size,
                              hipStream_t stream) {
    const float* inputs   = (const float*)d_in[0];   // [N, D] raw
    const float* codebook = (const float*)d_in[1];   // [K, D] raw
    float* out = (float*)d_out;

    // output layout (flat, return order)
    float* vq_loss = out;                                   // 1
    float* quant   = out + 1;                               // N*D (also x_n scratch)
    float* probs   = quant + (size_t)N_ROWS * D_DIM;        // N*K
    float* ppl     = probs + (size_t)N_ROWS * K_CODES;      // 1
    float* idxout  = ppl + 1;                               // N

    // workspace layout (~25.3 MB)
    float* cbn     = (float*)d_ws;                          // K*D fp32
    float* counts  = cbn + (size_t)K_CODES * D_DIM;         // K
    float* rowloss = counts + K_CODES;                      // N
    unsigned short* Ah = (unsigned short*)(rowloss + N_ROWS);   // N*D bf16 hi
    unsigned short* Al = Ah + (size_t)N_ROWS * D_DIM;           // N*D bf16 lo
    unsigned short* Bh = Al + (size_t)N_ROWS * D_DIM;           // K*D bf16 hi
    unsigned short* Bl = Bh + (size_t)K_CODES * D_DIM;          // K*D bf16 lo

    hipMemsetAsync(counts, 0, K_CODES * sizeof(float), stream);
    norm_rows_np_kernel<<<K_CODES / NORM_ROWS_PER_BLK, 256, 0, stream>>>(codebook, cbn, Bh, Bl);
    norm_rows_np_kernel<<<N_ROWS / NORM_ROWS_PER_BLK, 256, 0, stream>>>(inputs, quant, Ah, Al);
    gemm_bf16x3_kernel<<<dim3(K_CODES / 256, N_ROWS / 256), 512, 0, stream>>>(Ah, Al, Bh, Bl, probs);
    rowpass_kernel<<<N_ROWS / 4, 256, 0, stream>>>(probs, cbn, quant, idxout, counts, rowloss);
    finalize_kernel<<<1, 256, 0, stream>>>(rowloss, counts, vq_loss, ppl);
}